// Round 1
// baseline (326.775 us; speedup 1.0000x reference)
//
#include <hip/hip_runtime.h>
#include <hip/hip_bf16.h>

#define NPTS 8192
#define NB 4
#define NC 13
#define KTOP 16
#define TM 512       // m-tile (float4 elements) staged per iteration
#define NTILE (NPTS / TM)
#define CAP 128      // per-thread candidate capacity

// score s = xn . xm - 0.5*||xm||^2  (xm.w holds -0.5*||xm||^2)
// dist = ||xn||^2 - 2*s  -> larger s == nearer neighbor
__device__ __forceinline__ float score4(const float4 xn, const float4 xm) {
    return fmaf(xn.x, xm.x, fmaf(xn.y, xm.y, fmaf(xn.z, xm.z, xm.w)));
}

// monotone map f32 -> u32 (ascending)
__device__ __forceinline__ unsigned sortable(float s) {
    unsigned u = __float_as_uint(s);
    unsigned mask = (u & 0x80000000u) ? 0xFFFFFFFFu : 0x80000000u;
    return u ^ mask;
}

// maintain 16 largest u64 keys; keys are guaranteed pairwise distinct,
// so replace-by-equality with the current min is unique and correct.
__device__ __forceinline__ void insert16(unsigned long long k,
                                         unsigned long long key[16],
                                         unsigned long long &kmin) {
    if (k > kmin) {
        #pragma unroll
        for (int i = 0; i < 16; ++i) key[i] = (key[i] == kmin) ? k : key[i];
        unsigned long long m = key[0];
        #pragma unroll
        for (int i = 1; i < 16; ++i) m = (key[i] < m) ? key[i] : m;
        kmin = m;
    }
}

// ---------------- kernel A: transpose + softmax prep ----------------
__global__ __launch_bounds__(256) void prep_kernel(
    const float* __restrict__ logits, const float* __restrict__ xyz,
    const float* __restrict__ rgb,
    float4* __restrict__ xyzt, float4* __restrict__ rgbt,
    float4* __restrict__ probst)
{
    int gid = blockIdx.x * 256 + threadIdx.x;      // 0 .. B*N-1
    int b = gid >> 13, n = gid & (NPTS - 1);

    const float* xb = xyz + b * 3 * NPTS;
    float x0 = xb[n], x1 = xb[NPTS + n], x2 = xb[2 * NPTS + n];
    xyzt[gid] = make_float4(x0, x1, x2, -0.5f * (x0 * x0 + x1 * x1 + x2 * x2));

    const float* rb = rgb + b * 3 * NPTS;
    rgbt[gid] = make_float4(rb[n], rb[NPTS + n], rb[2 * NPTS + n], 0.f);

    const float* lb = logits + b * NC * NPTS;
    float l[NC];
    float mx = -1e30f;
    #pragma unroll
    for (int c = 0; c < NC; ++c) { l[c] = lb[c * NPTS + n]; mx = fmaxf(mx, l[c]); }
    float sum = 0.f;
    #pragma unroll
    for (int c = 0; c < NC; ++c) { l[c] = __expf(l[c] - mx); sum += l[c]; }
    float inv = 1.0f / sum;
    #pragma unroll
    for (int c = 0; c < NC; ++c) l[c] *= inv;

    float4* dst = probst + (size_t)gid * 4;
    dst[0] = make_float4(l[0], l[1], l[2], l[3]);
    dst[1] = make_float4(l[4], l[5], l[6], l[7]);
    dst[2] = make_float4(l[8], l[9], l[10], l[11]);
    dst[3] = make_float4(l[12], 0.f, 0.f, 0.f);   // pads: |0-0| contributes 0
}

// ---------------- kernel B: exact top-16 + loss partials ----------------
// block: 256 threads = 64 rows x 4 m-quarters. grid: B * (N/64) = 512.
__global__ __launch_bounds__(256, 2) void topk_loss_kernel(
    const float4* __restrict__ xyzt, const float4* __restrict__ rgbt,
    const float4* __restrict__ probst, float* __restrict__ partials)
{
    __shared__ float4 s_tile[TM];                         // 8 KB
    __shared__ unsigned long long s_u64[CAP * 256 / 4];   // 64 KB: cand u16 / merge u64
    __shared__ float s_thr[256];                          // 1 KB

    const int tid = threadIdx.x;
    const int r = tid & 63;          // row within block
    const int q = tid >> 6;          // m-quarter == wave id (wave-uniform)
    const int bidx = blockIdx.x;
    const int b = bidx >> 7;                         // 128 row-blocks per batch
    const int n = ((bidx & 127) << 6) + r;           // this thread's row
    const float4* xb = xyzt + b * NPTS;

    const float4 xn = xb[n];

    // ---- phase 1: 16 bucket maxes over disjoint subsets (branchless) ----
    float bk[16];
    #pragma unroll
    for (int i = 0; i < 16; ++i) bk[i] = -1e30f;

    for (int t = 0; t < NTILE; ++t) {
        __syncthreads();
        s_tile[tid]       = xb[t * TM + tid];
        s_tile[tid + 256] = xb[t * TM + tid + 256];
        __syncthreads();
        for (int jj = 0; jj < 8; ++jj) {
            #pragma unroll
            for (int u = 0; u < 16; ++u) {
                float4 xm = s_tile[(jj * 16 + u) * 4 + q];   // wave-uniform -> broadcast
                float s = score4(xn, xm);
                bk[u] = fmaxf(bk[u], s);
            }
        }
    }

    // min of 16 distinct elements' scores  =>  <= s_(16) of the row
    float tmin = bk[0];
    #pragma unroll
    for (int i = 1; i < 16; ++i) tmin = fminf(tmin, bk[i]);
    s_thr[tid] = tmin;
    __syncthreads();
    const float thr = fmaxf(fmaxf(s_thr[r], s_thr[64 + r]),
                            fmaxf(s_thr[128 + r], s_thr[192 + r]));

    // ---- phase 2: collect candidates with s >= thr ----
    unsigned short* s_cand = (unsigned short*)s_u64;
    int cnt = 0;
    for (int t = 0; t < NTILE; ++t) {
        __syncthreads();
        s_tile[tid]       = xb[t * TM + tid];
        s_tile[tid + 256] = xb[t * TM + tid + 256];
        __syncthreads();
        #pragma unroll 4
        for (int j = 0; j < TM / 4; ++j) {
            float4 xm = s_tile[j * 4 + q];
            float s = score4(xn, xm);
            if (s >= thr) {
                if (cnt < CAP) s_cand[tid * CAP + cnt] = (unsigned short)(t * TM + j * 4 + q);
                cnt++;
            }
        }
    }
    cnt = min(cnt, CAP);

    // ---- phase 3a: per-thread exact top-16 over own candidates ----
    unsigned long long key[16];
    #pragma unroll
    for (int i = 0; i < 16; ++i)
        key[i] = (unsigned long long)(q * 16 + i);   // distinct sentinels (< 8192)
    unsigned long long kmin = key[0];
    #pragma unroll
    for (int i = 1; i < 16; ++i) kmin = (key[i] < kmin) ? key[i] : kmin;

    for (int c = 0; c < cnt; ++c) {
        int mi = s_cand[tid * CAP + c];
        float4 xm = xb[mi];
        float s = score4(xn, xm);
        unsigned long long k =
            ((unsigned long long)sortable(s) << 13) | (unsigned long long)(8191 - mi);
        insert16(k, key, kmin);
    }

    // ---- phase 3b: merge 4 quarter-lists per row ----
    __syncthreads();                      // everyone done reading s_cand
    unsigned long long* s_mk = s_u64;     // 64 rows x 64 keys = 32 KB (fits)
    #pragma unroll
    for (int i = 0; i < 16; ++i) s_mk[r * 64 + q * 16 + i] = key[i];
    __syncthreads();

    float blocksum = 0.0f;
    if (q == 0) {
        for (int c = 16; c < 64; ++c) insert16(s_mk[r * 64 + c], key, kmin);

        // ---- phase 4: loss over the exact 16 nearest neighbors ----
        const int b8 = b * NPTS;
        float4 crgb = rgbt[b8 + n];
        const float4* cp = probst + (size_t)(b8 + n) * 4;
        float4 cp0 = cp[0], cp1 = cp[1], cp2 = cp[2], cp3 = cp[3];
        float acc = 0.f;
        #pragma unroll
        for (int i = 0; i < 16; ++i) {
            int mi = 8191 - (int)(key[i] & 0x1FFFull);
            float4 nr = rgbt[b8 + mi];
            const float4* np4 = probst + (size_t)(b8 + mi) * 4;
            float4 p0 = np4[0], p1 = np4[1], p2 = np4[2], p3 = np4[3];
            float dx = crgb.x - nr.x, dy = crgb.y - nr.y, dz = crgb.z - nr.z;
            float rd = sqrtf(fmaf(dx, dx, fmaf(dy, dy, dz * dz)));
            float pd = 0.f;
            pd += fabsf(cp0.x - p0.x) + fabsf(cp0.y - p0.y) + fabsf(cp0.z - p0.z) + fabsf(cp0.w - p0.w);
            pd += fabsf(cp1.x - p1.x) + fabsf(cp1.y - p1.y) + fabsf(cp1.z - p1.z) + fabsf(cp1.w - p1.w);
            pd += fabsf(cp2.x - p2.x) + fabsf(cp2.y - p2.y) + fabsf(cp2.z - p2.z) + fabsf(cp2.w - p2.w);
            pd += fabsf(cp3.x - p3.x) + fabsf(cp3.y - p3.y) + fabsf(cp3.z - p3.z) + fabsf(cp3.w - p3.w);
            float w = __expf(-10.0f * rd);
            acc = fmaf(w, pd, acc);
        }
        blocksum = acc;

        // deterministic wave reduce (lanes 0..63 of wave 0)
        for (int off = 32; off > 0; off >>= 1) blocksum += __shfl_down(blocksum, off);
        if (r == 0) partials[bidx] = blocksum;
    }
}

// ---------------- kernel C: final reduce ----------------
__global__ __launch_bounds__(256) void reduce_kernel(const float* __restrict__ partials,
                                                     float* __restrict__ out) {
    __shared__ float s[256];
    int tid = threadIdx.x;
    s[tid] = partials[tid] + partials[tid + 256];
    __syncthreads();
    if (tid < 128) s[tid] += s[tid + 128];
    __syncthreads();
    if (tid < 64) {
        float x = s[tid] + s[tid + 64];
        for (int off = 32; off > 0; off >>= 1) x += __shfl_down(x, off);
        if (tid == 0) out[0] = x * (1.0f / (float)(NB * NPTS * KTOP));
    }
}

extern "C" void kernel_launch(void* const* d_in, const int* in_sizes, int n_in,
                              void* d_out, int out_size, void* d_ws, size_t ws_size,
                              hipStream_t stream) {
    (void)in_sizes; (void)n_in; (void)out_size; (void)ws_size;
    const float* logits = (const float*)d_in[0];
    const float* xyz    = (const float*)d_in[1];
    const float* rgb    = (const float*)d_in[2];

    float4* xyzt   = (float4*)d_ws;            // 32768 float4  (512 KB)
    float4* rgbt   = xyzt + NB * NPTS;         // 32768 float4  (512 KB)
    float4* probst = rgbt + NB * NPTS;         // 131072 float4 (2 MB)
    float*  partials = (float*)(probst + (size_t)NB * NPTS * 4);  // 512 floats

    prep_kernel<<<NB * NPTS / 256, 256, 0, stream>>>(logits, xyz, rgb, xyzt, rgbt, probst);
    topk_loss_kernel<<<NB * (NPTS / 64), 256, 0, stream>>>(xyzt, rgbt, probst, partials);
    reduce_kernel<<<1, 256, 0, stream>>>(partials, (float*)d_out);
}

// Round 2
// 266.632 us; speedup vs baseline: 1.2256x; 1.2256x over previous
//
#include <hip/hip_runtime.h>
#include <hip/hip_bf16.h>

#define NPTS 8192
#define NB 4
#define NC 13
#define KTOP 16
#define P 16          // m-slices (combs) per row: lane p owns m with m%16==p
#define MS (NPTS/P)   // 512 m per slice
#define RPB 32        // rows per block (256 thr = 4 waves * 4 g * 16 p, 2 rows/lane)
#define CAP 8         // candidate capacity per (row, slice)

typedef unsigned long long ull;

// score s = xn . xm - 0.5*||xm||^2  (xm.w = -0.5*||xm||^2); larger s == nearer
__device__ __forceinline__ float score4(const float4 xn, const float4 xm) {
    return fmaf(xn.x, xm.x, fmaf(xn.y, xm.y, fmaf(xn.z, xm.z, xm.w)));
}
__device__ __forceinline__ unsigned sortable(float s) {
    unsigned u = __float_as_uint(s);
    return u ^ ((u & 0x80000000u) ? 0xFFFFFFFFu : 0x80000000u);
}
// top-16 floats, min-replacement (values pairwise distinct w.p. 1)
__device__ __forceinline__ void insertf(float v, float t[16], float &tmin) {
    if (v > tmin) {
        #pragma unroll
        for (int i = 0; i < 16; ++i) t[i] = (t[i] == tmin) ? v : t[i];
        float m = t[0];
        #pragma unroll
        for (int i = 1; i < 16; ++i) m = fminf(m, t[i]);
        tmin = m;
    }
}
// top-16 u64 keys (keys pairwise distinct by construction)
__device__ __forceinline__ void insert16(ull k, ull key[16], ull &kmin) {
    if (k > kmin) {
        #pragma unroll
        for (int i = 0; i < 16; ++i) key[i] = (key[i] == kmin) ? k : key[i];
        ull m = key[0];
        #pragma unroll
        for (int i = 1; i < 16; ++i) m = (key[i] < m) ? key[i] : m;
        kmin = m;
    }
}

// threshold <= s_(16) of the row: exact top-16 of the 64 bucket-maxes across
// the 4-lane group (xor 1,2), then max of group mins (xor 4,8).
__device__ __forceinline__ float row_threshold(const float bk[16]) {
    float t[16];
    #pragma unroll
    for (int i = 0; i < 16; ++i) t[i] = bk[i];
    float tmin = t[0];
    #pragma unroll
    for (int i = 1; i < 16; ++i) tmin = fminf(tmin, t[i]);
    #pragma unroll
    for (int rr = 0; rr < 2; ++rr) {
        const int mask = 1 << rr;
        float rv[16];
        #pragma unroll
        for (int i = 0; i < 16; ++i) rv[i] = __shfl_xor(t[i], mask);
        #pragma unroll
        for (int i = 0; i < 16; ++i) insertf(rv[i], t, tmin);
    }
    tmin = fmaxf(tmin, __shfl_xor(tmin, 4));
    tmin = fmaxf(tmin, __shfl_xor(tmin, 8));
    return tmin;
}

// phases 3+4 for one row: exact top-16 via per-slice insert + 4-round shfl
// merge; then lane p computes neighbor p's loss term; returns row sum (all lanes).
__device__ __forceinline__ float row_finish(const float4* __restrict__ xb, const float4 xn,
        int nrow, int cnt, const unsigned short* s_cand, int cbase, int p, int b8,
        const float4* __restrict__ rgbt, const float4* __restrict__ probst) {
    ull key[16];
    #pragma unroll
    for (int i = 0; i < 16; ++i) key[i] = (ull)(p * 16 + i);  // distinct across p-lanes
    ull kmin = key[0];
    for (int c = 0; c < cnt; ++c) {
        int mm = s_cand[cbase + c];
        int mi = mm * P + p;
        float s = score4(xn, xb[mi]);
        ull k = ((ull)sortable(s) << 13) | (ull)(8191 - mi);  // tie: lower idx wins
        insert16(k, key, kmin);
    }
    #pragma unroll
    for (int rr = 0; rr < 4; ++rr) {
        const int mask = 1 << rr;
        ull rv[16];
        #pragma unroll
        for (int i = 0; i < 16; ++i) rv[i] = __shfl_xor(key[i], mask);
        #pragma unroll
        for (int i = 0; i < 16; ++i) insert16(rv[i], key, kmin);
    }
    // lane p takes neighbor p (static-index select chain, no scratch)
    ull kk = key[0];
    #pragma unroll
    for (int i = 1; i < 16; ++i) kk = (p == i) ? key[i] : kk;
    int mi = 8191 - (int)(kk & 0x1FFFull);

    float4 crgb = rgbt[b8 + nrow];
    const float4* cp = probst + (size_t)(b8 + nrow) * 4;
    float4 cp0 = cp[0], cp1 = cp[1], cp2 = cp[2], cp3 = cp[3];
    float4 nr = rgbt[b8 + mi];
    const float4* np4 = probst + (size_t)(b8 + mi) * 4;
    float4 q0 = np4[0], q1 = np4[1], q2 = np4[2], q3 = np4[3];
    float dx = crgb.x - nr.x, dy = crgb.y - nr.y, dz = crgb.z - nr.z;
    float rd = sqrtf(fmaf(dx, dx, fmaf(dy, dy, dz * dz)));
    float pd = fabsf(cp0.x-q0.x)+fabsf(cp0.y-q0.y)+fabsf(cp0.z-q0.z)+fabsf(cp0.w-q0.w)
             + fabsf(cp1.x-q1.x)+fabsf(cp1.y-q1.y)+fabsf(cp1.z-q1.z)+fabsf(cp1.w-q1.w)
             + fabsf(cp2.x-q2.x)+fabsf(cp2.y-q2.y)+fabsf(cp2.z-q2.z)+fabsf(cp2.w-q2.w)
             + fabsf(cp3.x-q3.x)+fabsf(cp3.y-q3.y)+fabsf(cp3.z-q3.z)+fabsf(cp3.w-q3.w);
    float term = __expf(-10.0f * rd) * pd;
    #pragma unroll
    for (int rr = 0; rr < 4; ++rr) term += __shfl_xor(term, 1 << rr);
    return term;
}

// ---------------- kernel A: transpose + softmax prep ----------------
__global__ __launch_bounds__(256) void prep_kernel(
    const float* __restrict__ logits, const float* __restrict__ xyz,
    const float* __restrict__ rgb,
    float4* __restrict__ xyzt, float4* __restrict__ rgbt,
    float4* __restrict__ probst)
{
    int gid = blockIdx.x * 256 + threadIdx.x;      // 0 .. B*N-1
    int b = gid >> 13, n = gid & (NPTS - 1);

    const float* xb = xyz + b * 3 * NPTS;
    float x0 = xb[n], x1 = xb[NPTS + n], x2 = xb[2 * NPTS + n];
    xyzt[gid] = make_float4(x0, x1, x2, -0.5f * (x0 * x0 + x1 * x1 + x2 * x2));

    const float* rb = rgb + b * 3 * NPTS;
    rgbt[gid] = make_float4(rb[n], rb[NPTS + n], rb[2 * NPTS + n], 0.f);

    const float* lb = logits + b * NC * NPTS;
    float l[NC];
    float mx = -1e30f;
    #pragma unroll
    for (int c = 0; c < NC; ++c) { l[c] = lb[c * NPTS + n]; mx = fmaxf(mx, l[c]); }
    float sum = 0.f;
    #pragma unroll
    for (int c = 0; c < NC; ++c) { l[c] = __expf(l[c] - mx); sum += l[c]; }
    float inv = 1.0f / sum;
    #pragma unroll
    for (int c = 0; c < NC; ++c) l[c] *= inv;

    float4* dst = probst + (size_t)gid * 4;
    dst[0] = make_float4(l[0], l[1], l[2], l[3]);
    dst[1] = make_float4(l[4], l[5], l[6], l[7]);
    dst[2] = make_float4(l[8], l[9], l[10], l[11]);
    dst[3] = make_float4(l[12], 0.f, 0.f, 0.f);   // pads contribute |0-0| = 0
}

// ---------------- kernel B: exact top-16 + loss ----------------
// 256 threads = 4 waves; lane = g*16+p; each lane: 2 rows x slice p.
// grid = NB*NPTS/RPB = 1024 blocks.
__global__ __launch_bounds__(256, 4) void topk_loss_kernel(
    const float4* __restrict__ xyzt, const float4* __restrict__ rgbt,
    const float4* __restrict__ probst, float* __restrict__ partials)
{
    __shared__ unsigned short s_cand[RPB * P * CAP];   // 8 KB
    __shared__ float s_w[4];

    const int tid = threadIdx.x;
    const int w = tid >> 6, lane = tid & 63;
    const int p = lane & 15, g = lane >> 4;
    const int b = blockIdx.x >> 8;                 // 256 blocks per batch
    const int base = (blockIdx.x & 255) * RPB;
    const int rl0 = w * 8 + g * 2;                 // local rows rl0, rl0+1
    const int n0 = base + rl0, n1 = n0 + 1;
    const int b8 = b * NPTS;
    const float4* xb = xyzt + b8;
    const float4 xn0 = xb[n0], xn1 = xb[n1];

    // ---- phase 1: 16 bucket maxes per (row, slice); coalesced, no LDS ----
    float bk0[16], bk1[16];
    #pragma unroll
    for (int i = 0; i < 16; ++i) { bk0[i] = -3.0e38f; bk1[i] = -3.0e38f; }

    for (int mm = 0; mm < MS; mm += 16) {
        #pragma unroll
        for (int u = 0; u < 16; ++u) {
            float4 xm = xb[(mm + u) * P + p];      // all 64 lanes: same 256B window
            bk0[u] = fmaxf(bk0[u], score4(xn0, xm));
            bk1[u] = fmaxf(bk1[u], score4(xn1, xm));
        }
    }
    const float thr0 = row_threshold(bk0);
    const float thr1 = row_threshold(bk1);

    // ---- phase 2: rescan slice, collect candidates with s >= thr ----
    const int cb0 = (rl0 * P + p) * CAP;
    const int cb1 = ((rl0 + 1) * P + p) * CAP;
    int cnt0 = 0, cnt1 = 0;
    #pragma unroll 4
    for (int mm = 0; mm < MS; ++mm) {
        float4 xm = xb[mm * P + p];
        float s0 = score4(xn0, xm);
        float s1 = score4(xn1, xm);
        if (s0 >= thr0) { s_cand[cb0 + min(cnt0, CAP - 1)] = (unsigned short)mm; cnt0++; }
        if (s1 >= thr1) { s_cand[cb1 + min(cnt1, CAP - 1)] = (unsigned short)mm; cnt1++; }
    }
    cnt0 = min(cnt0, CAP); cnt1 = min(cnt1, CAP);

    // ---- phases 3+4 ----
    float t0 = row_finish(xb, xn0, n0, cnt0, s_cand, cb0, p, b8, rgbt, probst);
    float t1 = row_finish(xb, xn1, n1, cnt1, s_cand, cb1, p, b8, rgbt, probst);

    float blocksum = (p == 0) ? (t0 + t1) : 0.0f;
    #pragma unroll
    for (int off = 32; off > 0; off >>= 1) blocksum += __shfl_down(blocksum, off);
    if (lane == 0) s_w[w] = blocksum;
    __syncthreads();
    if (tid == 0) partials[blockIdx.x] = s_w[0] + s_w[1] + s_w[2] + s_w[3];
}

// ---------------- kernel C: final reduce ----------------
__global__ __launch_bounds__(256) void reduce_kernel(const float* __restrict__ partials,
                                                     float* __restrict__ out) {
    __shared__ float s[256];
    int tid = threadIdx.x;
    s[tid] = partials[tid] + partials[tid + 256] + partials[tid + 512] + partials[tid + 768];
    __syncthreads();
    if (tid < 128) s[tid] += s[tid + 128];
    __syncthreads();
    if (tid < 64) {
        float x = s[tid] + s[tid + 64];
        for (int off = 32; off > 0; off >>= 1) x += __shfl_down(x, off);
        if (tid == 0) out[0] = x * (1.0f / (float)(NB * NPTS * KTOP));
    }
}

extern "C" void kernel_launch(void* const* d_in, const int* in_sizes, int n_in,
                              void* d_out, int out_size, void* d_ws, size_t ws_size,
                              hipStream_t stream) {
    (void)in_sizes; (void)n_in; (void)out_size; (void)ws_size;
    const float* logits = (const float*)d_in[0];
    const float* xyz    = (const float*)d_in[1];
    const float* rgb    = (const float*)d_in[2];

    float4* xyzt   = (float4*)d_ws;            // 32768 float4  (512 KB)
    float4* rgbt   = xyzt + NB * NPTS;         // 32768 float4  (512 KB)
    float4* probst = rgbt + NB * NPTS;         // 131072 float4 (2 MB)
    float*  partials = (float*)(probst + (size_t)NB * NPTS * 4);  // 1024 floats

    prep_kernel<<<NB * NPTS / 256, 256, 0, stream>>>(logits, xyz, rgb, xyzt, rgbt, probst);
    topk_loss_kernel<<<NB * NPTS / RPB, 256, 0, stream>>>(xyzt, rgbt, probst, partials);
    reduce_kernel<<<1, 256, 0, stream>>>(partials, (float*)d_out);
}

// Round 3
// 128.564 us; speedup vs baseline: 2.5417x; 2.0739x over previous
//
#include <hip/hip_runtime.h>
#include <hip/hip_bf16.h>

#define NPTS 8192
#define NB 4
#define NC 13
#define KTOP 16
#define RPB 32        // rows per block (4 waves x 8 rows)
#define CAP 56        // per-row candidate list capacity

typedef unsigned long long ull;

// score s = xn . xm - 0.5*||xm||^2  (xm.w = -0.5*||xm||^2); larger s == nearer
__device__ __forceinline__ float score4(const float4 xn, const float4 xm) {
    return fmaf(xn.x, xm.x, fmaf(xn.y, xm.y, fmaf(xn.z, xm.z, xm.w)));
}
__device__ __forceinline__ unsigned sortable(float s) {
    unsigned u = __float_as_uint(s);
    return u ^ ((u & 0x80000000u) ? 0xFFFFFFFFu : 0x80000000u);
}

// ---------------- kernel A: transpose + softmax prep ----------------
__global__ __launch_bounds__(256) void prep_kernel(
    const float* __restrict__ logits, const float* __restrict__ xyz,
    const float* __restrict__ rgb,
    float4* __restrict__ xyzt, float4* __restrict__ rgbt,
    float4* __restrict__ probst)
{
    int gid = blockIdx.x * 256 + threadIdx.x;      // 0 .. B*N-1
    int b = gid >> 13, n = gid & (NPTS - 1);

    const float* xb = xyz + b * 3 * NPTS;
    float x0 = xb[n], x1 = xb[NPTS + n], x2 = xb[2 * NPTS + n];
    xyzt[gid] = make_float4(x0, x1, x2, -0.5f * (x0 * x0 + x1 * x1 + x2 * x2));

    const float* rb = rgb + b * 3 * NPTS;
    rgbt[gid] = make_float4(rb[n], rb[NPTS + n], rb[2 * NPTS + n], 0.f);

    const float* lb = logits + b * NC * NPTS;
    float l[NC];
    float mx = -1e30f;
    #pragma unroll
    for (int c = 0; c < NC; ++c) { l[c] = lb[c * NPTS + n]; mx = fmaxf(mx, l[c]); }
    float sum = 0.f;
    #pragma unroll
    for (int c = 0; c < NC; ++c) { l[c] = __expf(l[c] - mx); sum += l[c]; }
    float inv = 1.0f / sum;
    #pragma unroll
    for (int c = 0; c < NC; ++c) l[c] *= inv;

    float4* dst = probst + (size_t)gid * 4;
    dst[0] = make_float4(l[0], l[1], l[2], l[3]);
    dst[1] = make_float4(l[4], l[5], l[6], l[7]);
    dst[2] = make_float4(l[8], l[9], l[10], l[11]);
    dst[3] = make_float4(l[12], 0.f, 0.f, 0.f);   // pads contribute |0-0| = 0
}

// ---------------- kernel B: exact top-16 + loss ----------------
// 256 threads = 4 waves; each wave owns 8 rows, lanes are m-parallel.
// grid = NB * NPTS / RPB = 1024 blocks.
__global__ __launch_bounds__(256, 4) void topk_loss_kernel(
    const float4* __restrict__ xyzt, const float4* __restrict__ rgbt,
    const float4* __restrict__ probst, float* __restrict__ partials)
{
    __shared__ unsigned int s_cnt[RPB];
    __shared__ ull s_list[RPB][CAP];     // 14.3 KB
    __shared__ float s_w[4];

    const int tid = threadIdx.x;
    const int w = tid >> 6, lane = tid & 63;
    const int b = blockIdx.x >> 8;                // 256 blocks per batch
    const int nbase = (blockIdx.x & 255) * RPB;   // block's first row
    const int rw = w * 8;                         // wave's first local row
    const int b8 = b * NPTS;
    const float4* xb = xyzt + b8;

    if (tid < RPB) s_cnt[tid] = 0;
    __syncthreads();

    // query points for this wave's 8 rows (broadcast loads)
    float4 xn[8];
    #pragma unroll
    for (int r = 0; r < 8; ++r) xn[r] = xb[nbase + rw + r];

    // ---- phase 1: per-(lane,row) running max over this lane's m-comb ----
    float bk[8];
    #pragma unroll
    for (int r = 0; r < 8; ++r) bk[r] = -3.0e38f;

    #pragma unroll 2
    for (int t = 0; t < NPTS / 64; ++t) {         // 128 tiles, 64 distinct pts each
        float4 pm = xb[t * 64 + lane];            // fully coalesced, no duplication
        #pragma unroll
        for (int r = 0; r < 8; ++r) bk[r] = fmaxf(bk[r], score4(xn[r], pm));
    }

    // ---- threshold: exact 16th-largest of the 64 lane-maxes per row ----
    // (dup-removal can only lower thr -> safe; thr <= s_(16) guaranteed)
    float thr[8];
    #pragma unroll
    for (int r = 0; r < 8; ++r) {
        float v = bk[r];
        float M = v;
        for (int it = 0; it < KTOP; ++it) {
            M = v;
            #pragma unroll
            for (int mk = 1; mk < 64; mk <<= 1) M = fmaxf(M, __shfl_xor(M, mk));
            v = (v == M) ? -3.0e38f : v;          // remove extracted max
        }
        thr[r] = M;                               // 16th extraction
    }

    // ---- phase 2: rescan, append candidates to per-row LDS lists ----
    #pragma unroll 2
    for (int t = 0; t < NPTS / 64; ++t) {
        float4 pm = xb[t * 64 + lane];
        int m = t * 64 + lane;
        #pragma unroll
        for (int r = 0; r < 8; ++r) {
            float s = score4(xn[r], pm);
            if (s >= thr[r]) {
                int row = rw + r;
                unsigned slot = atomicAdd(&s_cnt[row], 1u);   // ds_add_rtn
                if (slot < CAP)
                    s_list[row][slot] =
                        ((ull)sortable(s) << 13) | (ull)(8191 - m);  // low idx wins ties
            }
        }
    }
    __syncthreads();

    // ---- phase 3: rank-count selection + loss terms ----
    // 8 lanes per row; lane handles slots i0, i0+8, ...
    const int rl = lane >> 3;            // local row 0..7
    const int i0 = lane & 7;
    const int row = rw + rl;
    const int nrow = nbase + row;
    const int cnt = min((int)s_cnt[row], CAP);

    float4 crgb = rgbt[b8 + nrow];
    const float4* cp = probst + (size_t)(b8 + nrow) * 4;
    float4 cp0 = cp[0], cp1 = cp[1], cp2 = cp[2], cp3 = cp[3];

    float acc = 0.f;
    for (int j = i0; j < cnt; j += 8) {
        ull kj = s_list[row][j];
        int rank = 0;
        for (int j2 = 0; j2 < cnt; ++j2) rank += (s_list[row][j2] > kj);
        if (rank < KTOP) {                        // exact top-16 member
            int m = 8191 - (int)(kj & 0x1FFFull);
            float4 nr = rgbt[b8 + m];
            const float4* np4 = probst + (size_t)(b8 + m) * 4;
            float4 q0 = np4[0], q1 = np4[1], q2 = np4[2], q3 = np4[3];
            float dx = crgb.x - nr.x, dy = crgb.y - nr.y, dz = crgb.z - nr.z;
            float rd = sqrtf(fmaf(dx, dx, fmaf(dy, dy, dz * dz)));
            float pd = fabsf(cp0.x-q0.x)+fabsf(cp0.y-q0.y)+fabsf(cp0.z-q0.z)+fabsf(cp0.w-q0.w)
                     + fabsf(cp1.x-q1.x)+fabsf(cp1.y-q1.y)+fabsf(cp1.z-q1.z)+fabsf(cp1.w-q1.w)
                     + fabsf(cp2.x-q2.x)+fabsf(cp2.y-q2.y)+fabsf(cp2.z-q2.z)+fabsf(cp2.w-q2.w)
                     + fabsf(cp3.x-q3.x)+fabsf(cp3.y-q3.y)+fabsf(cp3.z-q3.z)+fabsf(cp3.w-q3.w);
            acc = fmaf(__expf(-10.0f * rd), pd, acc);
        }
    }

    // fixed-tree reduce: wave -> block -> partials
    #pragma unroll
    for (int off = 32; off > 0; off >>= 1) acc += __shfl_down(acc, off);
    if (lane == 0) s_w[w] = acc;
    __syncthreads();
    if (tid == 0) partials[blockIdx.x] = s_w[0] + s_w[1] + s_w[2] + s_w[3];
}

// ---------------- kernel C: final reduce ----------------
__global__ __launch_bounds__(256) void reduce_kernel(const float* __restrict__ partials,
                                                     float* __restrict__ out) {
    __shared__ float s[256];
    int tid = threadIdx.x;
    s[tid] = partials[tid] + partials[tid + 256] + partials[tid + 512] + partials[tid + 768];
    __syncthreads();
    if (tid < 128) s[tid] += s[tid + 128];
    __syncthreads();
    if (tid < 64) {
        float x = s[tid] + s[tid + 64];
        for (int off = 32; off > 0; off >>= 1) x += __shfl_down(x, off);
        if (tid == 0) out[0] = x * (1.0f / (float)(NB * NPTS * KTOP));
    }
}

extern "C" void kernel_launch(void* const* d_in, const int* in_sizes, int n_in,
                              void* d_out, int out_size, void* d_ws, size_t ws_size,
                              hipStream_t stream) {
    (void)in_sizes; (void)n_in; (void)out_size; (void)ws_size;
    const float* logits = (const float*)d_in[0];
    const float* xyz    = (const float*)d_in[1];
    const float* rgb    = (const float*)d_in[2];

    float4* xyzt   = (float4*)d_ws;            // 32768 float4  (512 KB)
    float4* rgbt   = xyzt + NB * NPTS;         // 32768 float4  (512 KB)
    float4* probst = rgbt + NB * NPTS;         // 131072 float4 (2 MB)
    float*  partials = (float*)(probst + (size_t)NB * NPTS * 4);  // 1024 floats

    prep_kernel<<<NB * NPTS / 256, 256, 0, stream>>>(logits, xyz, rgb, xyzt, rgbt, probst);
    topk_loss_kernel<<<NB * NPTS / RPB, 256, 0, stream>>>(xyzt, rgbt, probst, partials);
    reduce_kernel<<<1, 256, 0, stream>>>(partials, (float*)d_out);
}

// Round 4
// 116.756 us; speedup vs baseline: 2.7988x; 1.1011x over previous
//
#include <hip/hip_runtime.h>
#include <hip/hip_bf16.h>

#define NPTS 8192
#define NB 4
#define NC 13
#define KTOP 16
#define RPB 16        // rows per block: 4 waves x 4 rows
#define CAP 128       // per-row candidate capacity

typedef unsigned long long ull;

__device__ __forceinline__ float rfl(float x) {
    return __uint_as_float(__builtin_amdgcn_readfirstlane(__float_as_uint(x)));
}
__device__ __forceinline__ unsigned sortable(float s) {
    unsigned u = __float_as_uint(s);
    return u ^ ((u & 0x80000000u) ? 0xFFFFFFFFu : 0x80000000u);
}

// ---------------- kernel A: transpose + softmax prep ----------------
__global__ __launch_bounds__(256) void prep_kernel(
    const float* __restrict__ logits, const float* __restrict__ xyz,
    const float* __restrict__ rgb,
    float4* __restrict__ xyzt, float4* __restrict__ rgbt,
    float4* __restrict__ probst)
{
    int gid = blockIdx.x * 256 + threadIdx.x;      // 0 .. B*N-1
    int b = gid >> 13, n = gid & (NPTS - 1);

    const float* xb = xyz + b * 3 * NPTS;
    float x0 = xb[n], x1 = xb[NPTS + n], x2 = xb[2 * NPTS + n];
    xyzt[gid] = make_float4(x0, x1, x2, -0.5f * (x0 * x0 + x1 * x1 + x2 * x2));

    const float* rb = rgb + b * 3 * NPTS;
    rgbt[gid] = make_float4(rb[n], rb[NPTS + n], rb[2 * NPTS + n], 0.f);

    const float* lb = logits + b * NC * NPTS;
    float l[NC];
    float mx = -1e30f;
    #pragma unroll
    for (int c = 0; c < NC; ++c) { l[c] = lb[c * NPTS + n]; mx = fmaxf(mx, l[c]); }
    float sum = 0.f;
    #pragma unroll
    for (int c = 0; c < NC; ++c) { l[c] = __expf(l[c] - mx); sum += l[c]; }
    float inv = 1.0f / sum;
    #pragma unroll
    for (int c = 0; c < NC; ++c) l[c] *= inv;

    float4* dst = probst + (size_t)gid * 4;
    dst[0] = make_float4(l[0], l[1], l[2], l[3]);
    dst[1] = make_float4(l[4], l[5], l[6], l[7]);
    dst[2] = make_float4(l[8], l[9], l[10], l[11]);
    dst[3] = make_float4(l[12], 0.f, 0.f, 0.f);   // pads contribute |0-0| = 0
}

// ---------------- kernel B: exact top-16 + loss ----------------
// 256 threads = 4 waves; wave owns 4 rows (queries in SGPRs), lanes m-parallel.
// grid = NB * NPTS / RPB = 2048 blocks -> 8 blocks/CU, 32 waves/CU.
__global__ __launch_bounds__(256, 8) void topk_loss_kernel(
    const float4* __restrict__ xyzt, const float4* __restrict__ rgbt,
    const float4* __restrict__ probst, float* __restrict__ partials)
{
    __shared__ unsigned int s_cnt[RPB];
    __shared__ ull s_list[RPB][CAP];     // 16 KB
    __shared__ float s_wred[4];

    const int tid = threadIdx.x;
    const int w = tid >> 6, lane = tid & 63;
    const int b = blockIdx.x >> 9;                // 512 blocks per batch
    const int nbase = (blockIdx.x & 511) * RPB;
    const int rw = w * 4;                         // wave's first local row
    const int b8 = b * NPTS;
    const float4* xb = xyzt + b8;

    if (tid < RPB) s_cnt[tid] = 0;
    __syncthreads();

    // wave-uniform query coords -> SGPRs (readfirstlane forces scalarization)
    float sx[4], sy[4], sz[4];
    #pragma unroll
    for (int r = 0; r < 4; ++r) {
        float4 q = xb[nbase + rw + r];            // same addr across wave
        sx[r] = rfl(q.x); sy[r] = rfl(q.y); sz[r] = rfl(q.z);
    }

    // ---- phase 1: per-(lane,row) running max over this lane's m-comb ----
    float bk[4];
    #pragma unroll
    for (int r = 0; r < 4; ++r) bk[r] = -3.0e38f;

    #pragma unroll 2
    for (int t = 0; t < NPTS / 64; ++t) {
        float4 pm = xb[t * 64 + lane];            // coalesced, distinct per lane
        #pragma unroll
        for (int r = 0; r < 4; ++r) {
            float s = fmaf(sx[r], pm.x, fmaf(sy[r], pm.y, fmaf(sz[r], pm.z, pm.w)));
            bk[r] = fmaxf(bk[r], s);
        }
    }

    // ---- threshold: min over 8 buckets (8 lanes each) of bucket top-2 ----
    // 16 distinct point-scores >= thr  =>  thr <= s_(16): exact superset.
    float thr[4];
    #pragma unroll
    for (int r = 0; r < 4; ++r) {
        float m1 = bk[r], m2 = -3.0e38f;
        #pragma unroll
        for (int mk = 1; mk < 8; mk <<= 1) {      // merge top-2 within 8-lane bucket
            float p1 = __shfl_xor(m1, mk), p2 = __shfl_xor(m2, mk);
            float lo = fminf(m1, p1);
            m1 = fmaxf(m1, p1);
            m2 = fmaxf(lo, fmaxf(m2, p2));
        }
        #pragma unroll
        for (int mk = 8; mk < 64; mk <<= 1)       // min of 2nd-maxes across buckets
            m2 = fminf(m2, __shfl_xor(m2, mk));
        thr[r] = rfl(m2);
    }

    // ---- phase 2: rescan, append candidates with s >= thr ----
    #pragma unroll 2
    for (int t = 0; t < NPTS / 64; ++t) {
        float4 pm = xb[t * 64 + lane];
        int m = t * 64 + lane;
        #pragma unroll
        for (int r = 0; r < 4; ++r) {
            float s = fmaf(sx[r], pm.x, fmaf(sy[r], pm.y, fmaf(sz[r], pm.z, pm.w)));
            if (s >= thr[r]) {
                int row = rw + r;
                unsigned slot = atomicAdd(&s_cnt[row], 1u);
                if (slot < CAP)
                    s_list[row][slot] =
                        ((ull)sortable(s) << 13) | (ull)(8191 - m);  // low idx wins ties
            }
        }
    }
    __syncthreads();

    // ---- phase 3: rank-count selection + loss terms (16 lanes per row) ----
    const int row = tid >> 4;            // 0..15
    const int i0 = tid & 15;
    const int nrow = nbase + row;
    const int cnt = min((int)s_cnt[row], CAP);   // cnt >= 16 guaranteed

    float4 crgb = rgbt[b8 + nrow];
    const float4* cp = probst + (size_t)(b8 + nrow) * 4;
    float4 cp0 = cp[0], cp1 = cp[1], cp2 = cp[2], cp3 = cp[3];

    float acc = 0.f;
    for (int j = i0; j < cnt; j += 16) {
        ull kj = s_list[row][j];
        int rank = 0;
        for (int j2 = 0; j2 < cnt; ++j2) rank += (s_list[row][j2] > kj);
        if (rank < KTOP) {                        // exact top-16 member
            int m = 8191 - (int)(kj & 0x1FFFull);
            float4 nr = rgbt[b8 + m];
            const float4* np4 = probst + (size_t)(b8 + m) * 4;
            float4 q0 = np4[0], q1 = np4[1], q2 = np4[2], q3 = np4[3];
            float dx = crgb.x - nr.x, dy = crgb.y - nr.y, dz = crgb.z - nr.z;
            float rd = sqrtf(fmaf(dx, dx, fmaf(dy, dy, dz * dz)));
            float pd = fabsf(cp0.x-q0.x)+fabsf(cp0.y-q0.y)+fabsf(cp0.z-q0.z)+fabsf(cp0.w-q0.w)
                     + fabsf(cp1.x-q1.x)+fabsf(cp1.y-q1.y)+fabsf(cp1.z-q1.z)+fabsf(cp1.w-q1.w)
                     + fabsf(cp2.x-q2.x)+fabsf(cp2.y-q2.y)+fabsf(cp2.z-q2.z)+fabsf(cp2.w-q2.w)
                     + fabsf(cp3.x-q3.x)+fabsf(cp3.y-q3.y)+fabsf(cp3.z-q3.z)+fabsf(cp3.w-q3.w);
            acc = fmaf(__expf(-10.0f * rd), pd, acc);
        }
    }

    // fixed-tree deterministic reduce: wave -> block -> partials
    #pragma unroll
    for (int off = 32; off > 0; off >>= 1) acc += __shfl_down(acc, off);
    if (lane == 0) s_wred[w] = acc;
    __syncthreads();
    if (tid == 0) partials[blockIdx.x] = s_wred[0] + s_wred[1] + s_wred[2] + s_wred[3];
}

// ---------------- kernel C: final reduce (2048 partials) ----------------
__global__ __launch_bounds__(256) void reduce_kernel(const float* __restrict__ partials,
                                                     float* __restrict__ out) {
    __shared__ float s[256];
    int tid = threadIdx.x;
    float v = 0.f;
    #pragma unroll
    for (int i = 0; i < 8; ++i) v += partials[tid + 256 * i];
    s[tid] = v;
    __syncthreads();
    if (tid < 128) s[tid] += s[tid + 128];
    __syncthreads();
    if (tid < 64) {
        float x = s[tid] + s[tid + 64];
        for (int off = 32; off > 0; off >>= 1) x += __shfl_down(x, off);
        if (tid == 0) out[0] = x * (1.0f / (float)(NB * NPTS * KTOP));
    }
}

extern "C" void kernel_launch(void* const* d_in, const int* in_sizes, int n_in,
                              void* d_out, int out_size, void* d_ws, size_t ws_size,
                              hipStream_t stream) {
    (void)in_sizes; (void)n_in; (void)out_size; (void)ws_size;
    const float* logits = (const float*)d_in[0];
    const float* xyz    = (const float*)d_in[1];
    const float* rgb    = (const float*)d_in[2];

    float4* xyzt   = (float4*)d_ws;            // 32768 float4  (512 KB)
    float4* rgbt   = xyzt + NB * NPTS;         // 32768 float4  (512 KB)
    float4* probst = rgbt + NB * NPTS;         // 131072 float4 (2 MB)
    float*  partials = (float*)(probst + (size_t)NB * NPTS * 4);  // 2048 floats

    prep_kernel<<<NB * NPTS / 256, 256, 0, stream>>>(logits, xyz, rgb, xyzt, rgbt, probst);
    topk_loss_kernel<<<NB * NPTS / RPB, 256, 0, stream>>>(xyzt, rgbt, probst, partials);
    reduce_kernel<<<1, 256, 0, stream>>>(partials, (float*)d_out);
}